// Round 8
// baseline (101.167 us; speedup 1.0000x reference)
//
#include <hip/hip_runtime.h>
#include <stdint.h>

#define B_ 4
#define N_ 4096
#define Q_ 4096
#define K_ 32
#define E_ 32
#define R_ 16
#define F_ 53   // 3 rel_pos + 1 radius + 32 emb + 16 rbf + 1 dist

static constexpr int   NB   = 512;       // x-buckets per batch
static constexpr float XLO  = -64.0f;
static constexpr float INVW = 4.0f;      // bucket width 0.25

static constexpr int WPB    = 4;             // waves per block (1 query each)
static constexpr int THREADS = WPB * 64;     // 256
static constexpr int PASS1W = 768;           // pass-1 fixed window (atoms)
static constexpr int CAP    = 128;           // per-query candidate capacity
static constexpr int TILE   = K_ * F_;       // 1696 floats
static constexpr int NSLOT  = 2;
static constexpr int POOLB  = (WPB * CAP * 4 > NSLOT * TILE * 4)
                            ? (WPB * CAP * 4) : (NSLOT * TILE * 4);

__device__ __host__ __forceinline__ int xbucket(float v) {
    int i = (int)floorf((v - XLO) * INVW);
    return i < 0 ? 0 : (i > NB - 1 ? NB - 1 : i);
}

__device__ __forceinline__ void bitonic_sort64_u32(unsigned int& v, int lane) {
    #pragma unroll
    for (int k = 2; k <= 64; k <<= 1) {
        #pragma unroll
        for (int j = k >> 1; j > 0; j >>= 1) {
            unsigned int o = __shfl_xor(v, j);
            const bool asc = ((lane & k) == 0);
            const bool lower = ((lane & j) == 0);
            unsigned int mn = v < o ? v : o;
            unsigned int mx = v < o ? o : v;
            v = (lower == asc) ? mn : mx;
        }
    }
}

__device__ __forceinline__ void bitonic_sort64_u64(unsigned long long& v, int lane) {
    #pragma unroll
    for (int k = 2; k <= 64; k <<= 1) {
        #pragma unroll
        for (int j = k >> 1; j > 0; j >>= 1) {
            unsigned long long o = __shfl_xor(v, j);
            const bool asc = ((lane & k) == 0);
            const bool lower = ((lane & j) == 0);
            unsigned long long mn = v < o ? v : o;
            unsigned long long mx = v < o ? o : v;
            v = (lower == asc) ? mn : mx;
        }
    }
}

__device__ __forceinline__ void merge64_u64(unsigned long long& best,
                                            unsigned long long c, int lane) {
    unsigned long long rev = __shfl(c, 63 - lane);
    unsigned long long v = best < rev ? best : rev;
    #pragma unroll
    for (int j = 32; j > 0; j >>= 1) {
        unsigned long long o = __shfl_xor(v, j);
        const bool lower = ((lane & j) == 0);
        unsigned long long mn = v < o ? v : o;
        unsigned long long mx = v < o ? o : v;
        v = lower ? mn : mx;
    }
    best = v;
}

// ---- prep: bucket atoms (negated AoS + offsets) and bucket-sort queries by x.
// 2 blocks per batch: part 0 = atoms, part 1 = queries.
__global__ __launch_bounds__(1024)
void prep_kernel(const float* __restrict__ coords,
                 const int* __restrict__ atom_mask,
                 const float* __restrict__ qpts,
                 const int* __restrict__ query_mask,
                 float4* __restrict__ aos,
                 float4* __restrict__ qaos,
                 unsigned int* __restrict__ bstart)
{
    __shared__ unsigned int hist[NB], incl[NB], cur[NB];
    const int b    = blockIdx.x >> 1;
    const int part = blockIdx.x & 1;
    const int tid  = threadIdx.x;

    if (tid < NB) hist[tid] = 0;
    __syncthreads();

    if (part == 0) {
        for (int i = tid; i < N_; i += 1024) {
            const bool mv = atom_mask[b * N_ + i] != 0;
            const float x = mv ? coords[(size_t)(b * N_ + i) * 3] : 1e30f;
            atomicAdd(&hist[xbucket(x)], 1u);
        }
    } else {
        for (int i = tid; i < Q_; i += 1024)
            atomicAdd(&hist[xbucket(qpts[(size_t)(b * Q_ + i) * 3])], 1u);
    }
    __syncthreads();
    if (tid < NB) incl[tid] = hist[tid];
    __syncthreads();
    for (int off = 1; off < NB; off <<= 1) {
        unsigned int v = 0;
        if (tid < NB && tid >= off) v = incl[tid - off];
        __syncthreads();
        if (tid < NB) incl[tid] += v;
        __syncthreads();
    }
    if (tid < NB) cur[tid] = incl[tid] - hist[tid];
    __syncthreads();

    if (part == 0) {
        if (tid < NB) bstart[b * (NB + 1) + tid] = cur[tid];
        if (tid == 0) bstart[b * (NB + 1) + NB] = N_;
        for (int i = tid; i < N_; i += 1024) {
            const float* c = coords + (size_t)(b * N_ + i) * 3;
            const bool mv = atom_mask[b * N_ + i] != 0;
            const float nx = mv ? -c[0] : -1e30f;
            const float ny = mv ? -c[1] : -1e30f;
            const float nz = mv ? -c[2] : -1e30f;
            const unsigned int pos = atomicAdd(&cur[xbucket(-nx)], 1u);
            aos[(size_t)b * N_ + pos] =
                make_float4(nx, ny, nz, __uint_as_float((unsigned int)i));
        }
    } else {
        for (int i = tid; i < Q_; i += 1024) {
            const float* q = qpts + (size_t)(b * Q_ + i) * 3;
            const unsigned int qm = (query_mask[b * Q_ + i] != 0) ? 1u : 0u;
            const unsigned int pos = atomicAdd(&cur[xbucket(q[0])], 1u);
            qaos[(size_t)b * Q_ + pos] =
                make_float4(q[0], q[1], q[2],
                            __uint_as_float((unsigned int)i | (qm << 16)));
        }
    }
}

// ---------------- main kernel: 1 query per wave ----------------
__global__ __launch_bounds__(THREADS, 8)
void lfb_kernel(const float* __restrict__ coords,
                const int* __restrict__ atom_types,
                const float* __restrict__ radii,
                const float* __restrict__ embed,
                const float* __restrict__ centers,
                const float4* __restrict__ aos,
                const float4* __restrict__ qaos,
                const unsigned int* __restrict__ bstart,
                float* __restrict__ out)
{
    __shared__ __align__(16) unsigned char pool[POOLB]; // cand bufs / stage slots

    const int tid  = threadIdx.x;
    const int lane = tid & 63;
    const int wv   = tid >> 6;                        // 0..3
    const int b    = blockIdx.x >> 10;                // 1024 blocks per batch
    const int qslot = (blockIdx.x & 1023) * WPB + wv; // sorted-query slot

    const float4* aosb = aos + (size_t)b * N_;
    const unsigned int* bs = bstart + b * (NB + 1);

    const float4 qa = qaos[(size_t)b * Q_ + qslot];
    const float qx = qa.x, qy = qa.y, qz = qa.z;
    const unsigned int wq = __float_as_uint(qa.w);
    const int origq = (int)(wq & 0xFFFFu);
    const bool qm = (wq >> 16) & 1u;

    const float INFf = __uint_as_float(0x7F800000u);

    // ---- pass 1: fixed 768 x-nearest atoms -> valid upper bound Ts ----
    const int p0 = (int)bs[xbucket(qx)];
    int start = p0 - PASS1W / 2;
    start = start < 0 ? 0 : (start > N_ - PASS1W ? N_ - PASS1W : start);
    float mn = INFf;
    for (int bi = 0; bi < PASS1W; bi += 256) {
        float4 a[4];
        #pragma unroll
        for (int u = 0; u < 4; ++u) a[u] = aosb[start + bi + u * 64 + lane];
        #pragma unroll
        for (int u = 0; u < 4; ++u) {
            const float dx = qx + a[u].x;
            const float dy = qy + a[u].y;
            const float dz = qz + a[u].z;
            mn = fminf(mn, fmaf(dz, dz, fmaf(dy, dy, dx * dx)));
        }
    }
    unsigned int ts = __float_as_uint(mn);
    bitonic_sort64_u32(ts, lane);
    const unsigned int Ts = __shfl(ts, 31);    // 32 witness atoms have s <= Ts
    const unsigned int ST = Ts + 64u;          // fma-vs-exact slop (superset)
    // coverage window: every exact-top-32 atom has |dx| <= dT (one shot, no retry)
    float dT = __fsqrt_rn(__uint_as_float(ST));
    dT = __fmaf_rn(dT, 1.0001f, 1e-3f);
    const int lo = xbucket(qx - dT);
    const int hi = xbucket(qx + dT);
    const int s0 = (int)bs[lo];
    const int e0 = (int)bs[hi + 1];

    // ---- pass 2: ballot-collect window positions with s_bits <= ST ----
    unsigned int* cb = reinterpret_cast<unsigned int*>(pool) + wv * CAP;
    const unsigned long long lt = (1ull << lane) - 1ull;
    int cnt = 0;
    for (int bi = s0; bi < e0; bi += 256) {
        float4 a[4];
        #pragma unroll
        for (int u = 0; u < 4; ++u) {
            const int i = bi + u * 64 + lane;
            a[u] = aosb[i < e0 ? i : e0 - 1];
        }
        #pragma unroll
        for (int u = 0; u < 4; ++u) {
            const int i = bi + u * 64 + lane;
            const float dx = qx + a[u].x;
            const float dy = qy + a[u].y;
            const float dz = qz + a[u].z;
            const float sv = fmaf(dz, dz, fmaf(dy, dy, dx * dx));
            const bool p = (i < e0) && (__float_as_uint(sv) <= ST);
            const unsigned long long mm = __ballot(p);
            if (p) {
                const int sl = cnt + __popcll(mm & lt);
                if (sl < CAP) cb[sl] = (unsigned int)i;
            }
            cnt += __popcll(mm);
        }
    }

    // ---- pass 3 / fallback: exact (d_bits, orig_idx) top-32 ----
    unsigned long long key;
    if (cnt <= CAP) {
        unsigned long long best = ~0ull;
        const int nch = (cnt + 63) >> 6;
        for (int c = 0; c < nch; ++c) {
            const int slot = c * 64 + lane;
            unsigned long long v = ~0ull;
            if (slot < cnt) {
                const float4 a = aosb[cb[slot]];
                const float dx = __fadd_rn(qx, a.x);   // exact reference path
                const float dy = __fadd_rn(qy, a.y);
                const float dz = __fadd_rn(qz, a.z);
                const float sv = __fadd_rn(
                    __fadd_rn(__fmul_rn(dx, dx), __fmul_rn(dy, dy)),
                    __fmul_rn(dz, dz));
                const float d = __fsqrt_rn(__fadd_rn(sv, 1e-12f));
                v = ((unsigned long long)__float_as_uint(d) << 32)
                  | __float_as_uint(a.w);
            }
            bitonic_sort64_u64(v, lane);
            if (c == 0) best = v;
            else        merge64_u64(best, v, lane);
        }
        key = best;
    } else {
        // fallback (degenerate masks / flooded threshold): exact full-N scan
        key = ~0ull;
        for (int bi = 0; bi < N_; bi += 64) {
            const float4 a = aosb[bi + lane];
            const float dx = __fadd_rn(qx, a.x);
            const float dy = __fadd_rn(qy, a.y);
            const float dz = __fadd_rn(qz, a.z);
            const float sv = __fadd_rn(
                __fadd_rn(__fmul_rn(dx, dx), __fmul_rn(dy, dy)),
                __fmul_rn(dz, dz));
            const float d = __fsqrt_rn(__fadd_rn(sv, 1e-12f));
            const unsigned long long cand =
                ((unsigned long long)__float_as_uint(d) << 32)
                | __float_as_uint(a.w);
            const unsigned long long T = __shfl(key, 31);
            unsigned long long m = __ballot(cand < T);
            while (m) {
                const int src = __ffsll(m) - 1;
                m &= m - 1;
                const unsigned long long nk = __shfl(cand, src);
                const unsigned long long up = __shfl_up(key, 1);
                if (lane < K_) {
                    const unsigned long long repl =
                        (lane == 0) ? nk : (up <= nk ? nk : up);
                    key = (key <= nk) ? key : repl;
                }
            }
        }
    }

    const size_t BQK = (size_t)B_ * Q_ * K_;
    float* out_feat = out;
    float* out_mask = out + BQK * (size_t)F_;
    float* out_idx  = out_mask + BQK;
    float* out_dist = out_idx + BQK;

    const int flatq = b * Q_ + origq;

    // scalar outputs before the stage-overlay barrier
    if (lane < K_) {
        const float d = __uint_as_float((unsigned int)(key >> 32));
        const int  id = (int)(key & 0xFFFFFFFFull);
        const bool am = ((unsigned int)(key >> 32)) < 0x7F800000u;
        const bool nm = am && (d <= 5.0f) && qm;
        const size_t o = (size_t)flatq * K_ + lane;
        out_mask[o] = nm ? 1.0f : 0.0f;
        out_idx[o]  = am ? (float)id : -1.0f;
        out_dist[o] = nm ? d : 0.0f;
    }

    __syncthreads();   // all cand-buffer reads done before stage overlay

    // ---- feature build: 2 stage slots, 2 barrier rounds ----
    const float d_l  = __uint_as_float((unsigned int)(key >> 32));
    const int   id_l = (int)(key & 0xFFFFFFFFull) & (N_ - 1);
    const bool  am_l = ((unsigned int)(key >> 32)) < 0x7F800000u;
    const bool  nm_l = am_l && (d_l <= 5.0f) && qm;

    float* stagef = reinterpret_cast<float*>(pool);
    for (int r = 0; r < 2; ++r) {
        if ((wv >> 1) == r) {
            float* slotp = stagef + (size_t)(wv & 1) * TILE;
            if (lane < K_) {
                float* f = slotp + lane * F_;
                const float* cp = coords + (size_t)(b * N_ + id_l) * 3;
                f[0] = nm_l ? __fsub_rn(qx, cp[0]) : 0.0f;
                f[1] = nm_l ? __fsub_rn(qy, cp[1]) : 0.0f;
                f[2] = nm_l ? __fsub_rn(qz, cp[2]) : 0.0f;
                f[3] = nm_l ? radii[b * N_ + id_l] : 0.0f;

                const int t = atom_types[b * N_ + id_l];
                const float4* er4 = (const float4*)(embed + t * E_);
                #pragma unroll
                for (int ei = 0; ei < E_ / 4; ++ei) {
                    const float4 v = er4[ei];
                    f[4 + ei * 4 + 0] = nm_l ? v.x : 0.0f;
                    f[4 + ei * 4 + 1] = nm_l ? v.y : 0.0f;
                    f[4 + ei * 4 + 2] = nm_l ? v.z : 0.0f;
                    f[4 + ei * 4 + 3] = nm_l ? v.w : 0.0f;
                }

                const float NG = -(float)(256.0 / 25.0);   // -RBF_GAMMA
                #pragma unroll
                for (int rr = 0; rr < R_; ++rr) {
                    const float dd = __fsub_rn(d_l, centers[rr]);
                    const float a2 = __fmul_rn(dd, dd);
                    f[36 + rr] = nm_l ? expf(__fmul_rn(NG, a2)) : 0.0f;
                }
                f[52] = nm_l ? d_l : 0.0f;
            }
            // same-wave LDS in-order: copy sees this wave's writes w/o barrier
            const float4* s4 = (const float4*)slotp;
            float4* d4 = (float4*)(out_feat + (size_t)flatq * (size_t)TILE);
            for (int t4 = lane; t4 < TILE / 4; t4 += 64) d4[t4] = s4[t4];
        }
        __syncthreads();
    }
}

extern "C" void kernel_launch(void* const* d_in, const int* in_sizes, int n_in,
                              void* d_out, int out_size, void* d_ws, size_t ws_size,
                              hipStream_t stream) {
    const float* coords     = (const float*)d_in[0];
    const int*   atom_types = (const int*)d_in[1];
    const float* radii      = (const float*)d_in[2];
    const float* qpts       = (const float*)d_in[3];
    const int*   atom_mask  = (const int*)d_in[4];
    const int*   query_mask = (const int*)d_in[5];
    const float* embed      = (const float*)d_in[6];
    const float* centers    = (const float*)d_in[7];

    float4* aos  = (float4*)d_ws;                       // B*N float4
    float4* qaos = aos + (size_t)B_ * N_;               // B*Q float4
    unsigned int* bstart = (unsigned int*)(qaos + (size_t)B_ * Q_);

    prep_kernel<<<B_ * 2, 1024, 0, stream>>>(coords, atom_mask, qpts, query_mask,
                                             aos, qaos, bstart);

    dim3 grid((B_ * Q_) / WPB);
    dim3 block(THREADS);
    lfb_kernel<<<grid, block, 0, stream>>>(coords, atom_types, radii,
                                           embed, centers, aos, qaos, bstart,
                                           (float*)d_out);
}

// Round 9
// 73.216 us; speedup vs baseline: 1.3818x; 1.3818x over previous
//
#include <hip/hip_runtime.h>
#include <stdint.h>

#define B_ 4
#define N_ 4096
#define Q_ 4096
#define K_ 32
#define E_ 32
#define R_ 16
#define F_ 53   // 3 rel_pos + 1 radius + 32 emb + 16 rbf + 1 dist

static constexpr int WAVES   = 16;           // waves per block, 1 query each
static constexpr int THREADS = WAVES * 64;   // 1024
static constexpr int SUB     = 1024;         // pass-1 subsample (atoms)
static constexpr int CAPL    = 352;          // loose candidate capacity (u32 idx)
static constexpr int CAPT    = 64;           // tight candidate capacity
static constexpr int TILE    = K_ * F_;      // 1696 floats per query tile
static constexpr int NSLOT   = 4;            // stage slots time-shared by waves
static constexpr int POOLB   = NSLOT * TILE * 4;   // 27136 B >= cand area 26624 B

typedef float v2f __attribute__((ext_vector_type(2)));

// VOP3P packed fp32: 2 FP32 ops per instruction (per-half rounding == scalar rn)
__device__ __forceinline__ v2f pk_add(v2f a, v2f b) {
    v2f d; asm("v_pk_add_f32 %0, %1, %2" : "=v"(d) : "v"(a), "v"(b)); return d;
}
__device__ __forceinline__ v2f pk_mul(v2f a, v2f b) {
    v2f d; asm("v_pk_mul_f32 %0, %1, %2" : "=v"(d) : "v"(a), "v"(b)); return d;
}
__device__ __forceinline__ v2f pk_fma(v2f a, v2f b, v2f c) {
    v2f d; asm("v_pk_fma_f32 %0, %1, %2, %3" : "=v"(d) : "v"(a), "v"(b), "v"(c)); return d;
}
// packed squared distance (fma-space) for 2 atoms; coords pre-negated
__device__ __forceinline__ v2f pk_s2(v2f qx, v2f qy, v2f qz,
                                     v2f nx, v2f ny, v2f nz) {
    const v2f dx = pk_add(qx, nx);
    const v2f dy = pk_add(qy, ny);
    const v2f dz = pk_add(qz, nz);
    return pk_fma(dz, dz, pk_fma(dy, dy, pk_mul(dx, dx)));
}
// scalar replica of pk_s2 (bitwise-identical rounding sequence)
__device__ __forceinline__ float s2_fma(float qx, float qy, float qz,
                                        float nx, float ny, float nz) {
    const float dx = __fadd_rn(qx, nx);
    const float dy = __fadd_rn(qy, ny);
    const float dz = __fadd_rn(qz, nz);
    return __fmaf_rn(dz, dz, __fmaf_rn(dy, dy, __fmul_rn(dx, dx)));
}

__device__ __forceinline__ void bitonic_sort64_u32(unsigned int& v, int lane) {
    #pragma unroll
    for (int k = 2; k <= 64; k <<= 1) {
        #pragma unroll
        for (int j = k >> 1; j > 0; j >>= 1) {
            unsigned int o = __shfl_xor(v, j);
            const bool asc = ((lane & k) == 0);
            const bool lower = ((lane & j) == 0);
            unsigned int mn = v < o ? v : o;
            unsigned int mx = v < o ? o : v;
            v = (lower == asc) ? mn : mx;
        }
    }
}

__device__ __forceinline__ void bitonic_sort64_u64(unsigned long long& v, int lane) {
    #pragma unroll
    for (int k = 2; k <= 64; k <<= 1) {
        #pragma unroll
        for (int j = k >> 1; j > 0; j >>= 1) {
            unsigned long long o = __shfl_xor(v, j);
            const bool asc = ((lane & k) == 0);
            const bool lower = ((lane & j) == 0);
            unsigned long long mn = v < o ? v : o;
            unsigned long long mx = v < o ? o : v;
            v = (lower == asc) ? mn : mx;
        }
    }
}

__device__ __forceinline__ void merge64_u64(unsigned long long& best,
                                            unsigned long long c, int lane) {
    unsigned long long rev = __shfl(c, 63 - lane);
    unsigned long long v = best < rev ? best : rev;
    #pragma unroll
    for (int j = 32; j > 0; j >>= 1) {
        unsigned long long o = __shfl_xor(v, j);
        const bool lower = ((lane & j) == 0);
        unsigned long long mn = v < o ? v : o;
        unsigned long long mx = v < o ? o : v;
        v = lower ? mn : mx;
    }
    best = v;
}

__global__ __launch_bounds__(THREADS, 8)
void lfb_kernel(const float* __restrict__ coords,
                const int* __restrict__ atom_types,
                const float* __restrict__ radii,
                const float* __restrict__ qpts,
                const int* __restrict__ atom_mask,
                const int* __restrict__ query_mask,
                const float* __restrict__ embed,
                const float* __restrict__ centers,
                float* __restrict__ out)
{
    __shared__ __align__(16) float nsx[N_], nsy[N_], nsz[N_];  // NEGATED coords
    __shared__ __align__(16) unsigned char pool[POOLB];        // cand / stage

    const int tid  = threadIdx.x;
    const int lane = tid & 63;
    const int wv   = tid >> 6;
    const int bq0  = blockIdx.x * WAVES;
    const int b    = bq0 / Q_;

    // stage negated coords; masked atoms poisoned (-1e30 -> s == +inf bit-exact)
    for (int i = tid; i < N_; i += THREADS) {
        const float* c = coords + (size_t)(b * N_ + i) * 3;
        const bool mv = atom_mask[b * N_ + i] != 0;
        nsx[i] = mv ? -c[0] : -1e30f;
        nsy[i] = mv ? -c[1] : -1e30f;
        nsz[i] = mv ? -c[2] : -1e30f;
    }
    __syncthreads();

    const int bq = bq0 + wv;
    const float qx = qpts[(size_t)bq * 3 + 0];
    const float qy = qpts[(size_t)bq * 3 + 1];
    const float qz = qpts[(size_t)bq * 3 + 2];
    const v2f qx2 = {qx, qx}, qy2 = {qy, qy}, qz2 = {qz, qz};

    const float INFf = __uint_as_float(0x7F800000u);

    // ---- pass 1: LOOSE bound from first SUB atoms (any subset gives a valid
    //      upper bound: 32 distinct lane-min witnesses have s <= Ts) ----
    float l0 = INFf, l1 = INFf, l2 = INFf, l3 = INFf;
    for (int i = 0; i < SUB / 256; ++i) {
        const int a0 = i * 256 + lane * 4;
        const float4 X = *(const float4*)&nsx[a0];
        const float4 Y = *(const float4*)&nsy[a0];
        const float4 Z = *(const float4*)&nsz[a0];
        const v2f Xl = {X.x, X.y}, Xh = {X.z, X.w};
        const v2f Yl = {Y.x, Y.y}, Yh = {Y.z, Y.w};
        const v2f Zl = {Z.x, Z.y}, Zh = {Z.z, Z.w};
        const v2f sl = pk_s2(qx2, qy2, qz2, Xl, Yl, Zl);
        const v2f sh = pk_s2(qx2, qy2, qz2, Xh, Yh, Zh);
        l0 = fminf(l0, sl.x); l1 = fminf(l1, sl.y);
        l2 = fminf(l2, sh.x); l3 = fminf(l3, sh.y);
    }
    unsigned int tsl = __float_as_uint(fminf(fminf(l0, l1), fminf(l2, l3)));
    bitonic_sort64_u32(tsl, lane);
    const unsigned int STl = __shfl(tsl, 31) + 64u;  // loose collect threshold

    // ---- pass 2: collect loose candidates + track FULL-scan lane minima ----
    unsigned int* loose = reinterpret_cast<unsigned int*>(pool) + wv * CAPL;
    unsigned int* tight = reinterpret_cast<unsigned int*>(pool)
                        + WAVES * CAPL + wv * CAPT;
    const unsigned long long lt = (1ull << lane) - 1ull;
    int cnt = 0;
    float m0 = INFf, m1 = INFf, m2 = INFf, m3 = INFf;
    auto collect = [&](float s, int idx) {
        const bool p = __float_as_uint(s) <= STl;
        const unsigned long long m = __ballot(p);
        if (p) {
            const int sl = cnt + __popcll(m & lt);
            if (sl < CAPL) loose[sl] = (unsigned int)idx;
        }
        cnt += __popcll(m);
    };
    for (int i = 0; i < N_ / 256; ++i) {
        const int a0 = i * 256 + lane * 4;
        const float4 X = *(const float4*)&nsx[a0];
        const float4 Y = *(const float4*)&nsy[a0];
        const float4 Z = *(const float4*)&nsz[a0];
        const v2f Xl = {X.x, X.y}, Xh = {X.z, X.w};
        const v2f Yl = {Y.x, Y.y}, Yh = {Y.z, Y.w};
        const v2f Zl = {Z.x, Z.y}, Zh = {Z.z, Z.w};
        const v2f sl = pk_s2(qx2, qy2, qz2, Xl, Yl, Zl);
        const v2f sh = pk_s2(qx2, qy2, qz2, Xh, Yh, Zh);
        m0 = fminf(m0, sl.x); m1 = fminf(m1, sl.y);
        m2 = fminf(m2, sh.x); m3 = fminf(m3, sh.y);
        collect(sl.x, a0 + 0);
        collect(sl.y, a0 + 1);
        collect(sh.x, a0 + 2);
        collect(sh.y, a0 + 3);
    }
    // TIGHT bound from the full scan (identical quantity to r4's pass 1)
    unsigned int tst = __float_as_uint(fminf(fminf(m0, m1), fminf(m2, m3)));
    bitonic_sort64_u32(tst, lane);
    const unsigned int STt = __shfl(tst, 31) + 64u;  // covers exact top-32

    // exact reference re-key (rn ops, fixed association, eps, CR sqrt)
    auto rekey = [&](int id) -> unsigned long long {
        const float dx = __fadd_rn(qx, nsx[id]);
        const float dy = __fadd_rn(qy, nsy[id]);
        const float dz = __fadd_rn(qz, nsz[id]);
        const float sv = __fadd_rn(
            __fadd_rn(__fmul_rn(dx, dx), __fmul_rn(dy, dy)),
            __fmul_rn(dz, dz));
        const float d = __fsqrt_rn(__fadd_rn(sv, 1e-12f));
        return ((unsigned long long)__float_as_uint(d) << 32) | (unsigned int)id;
    };

    unsigned long long key;
    if (cnt <= CAPL) {
        // ---- refilter loose -> tight with STt (usually ~44 survive) ----
        int tcnt = 0;
        const int nchL = (cnt + 63) >> 6;
        for (int c = 0; c < nchL; ++c) {
            const int slot = c * 64 + lane;
            const bool valid = slot < cnt;
            const int id = valid ? (int)loose[slot] : 0;
            const float s = s2_fma(qx, qy, qz, nsx[id], nsy[id], nsz[id]);
            const bool p = valid && (__float_as_uint(s) <= STt);
            const unsigned long long m = __ballot(p);
            if (p) {
                const int sl = tcnt + __popcll(m & lt);
                if (sl < CAPT) tight[sl] = (unsigned int)id;
            }
            tcnt += __popcll(m);
        }
        if (tcnt <= CAPT) {
            // single-chunk exact sort
            unsigned long long v = (lane < tcnt) ? rekey((int)tight[lane]) : ~0ull;
            bitonic_sort64_u64(v, lane);
            key = v;
        } else {
            // rare: sort the whole loose set chunked
            unsigned long long best = ~0ull;
            for (int c = 0; c < nchL; ++c) {
                const int slot = c * 64 + lane;
                unsigned long long v =
                    (slot < cnt) ? rekey((int)loose[slot]) : ~0ull;
                bitonic_sort64_u64(v, lane);
                if (c == 0) best = v;
                else        merge64_u64(best, v, lane);
            }
            key = best;
        }
    } else {
        // fallback (degenerate masks / flooded threshold): exact streaming scan
        key = ~0ull;
        for (int base = 0; base < N_; base += 64) {
            const unsigned long long cand = rekey(base + lane);
            const unsigned long long T = __shfl(key, 31);
            unsigned long long m = __ballot(cand < T);
            while (m) {
                const int src = __ffsll(m) - 1;
                m &= m - 1;
                const unsigned long long nk = __shfl(cand, src);
                const unsigned long long up = __shfl_up(key, 1);
                if (lane < K_) {
                    const unsigned long long repl =
                        (lane == 0) ? nk : (up <= nk ? nk : up);
                    key = (key <= nk) ? key : repl;
                }
            }
        }
    }

    const size_t BQK = (size_t)B_ * Q_ * K_;
    float* out_feat = out;
    float* out_mask = out + BQK * (size_t)F_;
    float* out_idx  = out_mask + BQK;
    float* out_dist = out_idx + BQK;

    const bool qm = query_mask[bq] != 0;

    const float d_l  = __uint_as_float((unsigned int)(key >> 32));
    const int   id_l = (int)(key & 0xFFFFFFFFull) & (N_ - 1);
    const bool  am_l = ((unsigned int)(key >> 32)) < 0x7F800000u;  // d < inf
    const bool  nm_l = am_l && (d_l <= 5.0f) && qm;

    // scalar outputs before the stage-overlay barrier
    if (lane < K_) {
        const size_t o = (size_t)bq * K_ + lane;
        out_mask[o] = nm_l ? 1.0f : 0.0f;
        out_idx[o]  = am_l ? (float)id_l : -1.0f;
        out_dist[o] = nm_l ? d_l : 0.0f;
    }

    __syncthreads();   // all cand-buffer reads done before stage overlay

    // ---- feature build: NSLOT stage slots, 4 barrier rounds ----
    float* stagef = reinterpret_cast<float*>(pool);
    for (int r = 0; r < WAVES / NSLOT; ++r) {
        if ((wv >> 2) == r) {
            float* f0 = stagef + (size_t)(wv & (NSLOT - 1)) * TILE;
            if (lane < K_) {
                float* f = f0 + lane * F_;
                f[0] = nm_l ? __fadd_rn(qx, nsx[id_l]) : 0.0f;
                f[1] = nm_l ? __fadd_rn(qy, nsy[id_l]) : 0.0f;
                f[2] = nm_l ? __fadd_rn(qz, nsz[id_l]) : 0.0f;
                f[3] = nm_l ? radii[b * N_ + id_l] : 0.0f;

                const int t = atom_types[b * N_ + id_l];
                const float4* er4 = (const float4*)(embed + t * E_);
                #pragma unroll
                for (int e = 0; e < E_ / 4; ++e) {
                    const float4 v = er4[e];
                    f[4 + e * 4 + 0] = nm_l ? v.x : 0.0f;
                    f[4 + e * 4 + 1] = nm_l ? v.y : 0.0f;
                    f[4 + e * 4 + 2] = nm_l ? v.z : 0.0f;
                    f[4 + e * 4 + 3] = nm_l ? v.w : 0.0f;
                }

                const float NG = -(float)(256.0 / 25.0);   // -RBF_GAMMA
                #pragma unroll
                for (int rr = 0; rr < R_; ++rr) {
                    const float dd = __fsub_rn(d_l, centers[rr]);
                    const float a2 = __fmul_rn(dd, dd);
                    f[36 + rr] = nm_l ? expf(__fmul_rn(NG, a2)) : 0.0f;
                }
                f[52] = nm_l ? d_l : 0.0f;
            }
            // same-wave LDS in-order: copy sees this wave's writes w/o barrier
            const float4* s4 = (const float4*)f0;
            float4* d4 = (float4*)(out_feat + (size_t)bq * (size_t)TILE);
            for (int t4 = lane; t4 < TILE / 4; t4 += 64) d4[t4] = s4[t4];
        }
        __syncthreads();
    }
}

extern "C" void kernel_launch(void* const* d_in, const int* in_sizes, int n_in,
                              void* d_out, int out_size, void* d_ws, size_t ws_size,
                              hipStream_t stream) {
    const float* coords     = (const float*)d_in[0];
    const int*   atom_types = (const int*)d_in[1];
    const float* radii      = (const float*)d_in[2];
    const float* qpts       = (const float*)d_in[3];
    const int*   atom_mask  = (const int*)d_in[4];
    const int*   query_mask = (const int*)d_in[5];
    const float* embed      = (const float*)d_in[6];
    const float* centers    = (const float*)d_in[7];

    dim3 grid((B_ * Q_) / WAVES);
    dim3 block(THREADS);
    lfb_kernel<<<grid, block, 0, stream>>>(coords, atom_types, radii, qpts,
                                           atom_mask, query_mask, embed, centers,
                                           (float*)d_out);
}